// Round 1
// baseline (6550.252 us; speedup 1.0000x reference)
//
#include <hip/hip_runtime.h>
#include <cstdint>

#define B_SZ 64
#define T_SZ 2048
#define F_SZ 256
#define H_SZ 512

#if defined(__has_builtin)
#if __has_builtin(__builtin_amdgcn_fdot2)
#define HAVE_FDOT2 1
#endif
#endif
#ifndef HAVE_FDOT2
#define HAVE_FDOT2 0
#endif

typedef _Float16 half2v __attribute__((ext_vector_type(2)));

union H2U { uint32_t u; half2v h; _Float16 e[2]; };

__device__ __forceinline__ float fdot2f(uint32_t a, uint32_t b, float c) {
  H2U ua, ub; ua.u = a; ub.u = b;
#if HAVE_FDOT2
  return __builtin_amdgcn_fdot2(ua.h, ub.h, c, false);
#else
  return c + (float)ua.e[0] * (float)ub.e[0] + (float)ua.e[1] * (float)ub.e[1];
#endif
}

__device__ __forceinline__ uint32_t pack2h(float x, float y) {
  H2U v; v.e[0] = (_Float16)x; v.e[1] = (_Float16)y; return v.u;
}

__device__ __forceinline__ unsigned short f16bits(float x) {
  union { _Float16 h; unsigned short s; } v; v.h = (_Float16)x; return v.s;
}

// XOR-swizzle of 16B chunks within a 256-uint LDS row (breaks the
// 128B-aligned-column bank conflict for ds_read_b128; §6 G4).
__device__ __forceinline__ int swz(int c, int r) {
  return (((c >> 2) ^ (r & 7)) << 2) | (c & 3);
}

// ---------------------------------------------------------------------------
// Kernel 1: xp[m, n] = sum_k q[m,k] * W_ih[n,k] + b_ih[n] + b_hh[n]
// M = B*T = 131072, K = 256, N = 512.  fp16 dot2, fp32 accumulate.
// Writes xp into the [B,T,H] region of d_out (overwritten in place by rnn).
// ---------------------------------------------------------------------------
__global__ __launch_bounds__(256) void proj_kernel(
    const float* __restrict__ q, const float* __restrict__ w_ih,
    const float* __restrict__ b_ih, const float* __restrict__ b_hh,
    float* __restrict__ xp) {
  // k-pair-major transposed tiles (dot2 consumes k-pairs); +4 pad keeps 16B
  // alignment for b128 reads and breaks write conflicts.
  __shared__ uint32_t lds_a[16][128 + 4];
  __shared__ uint32_t lds_b[16][128 + 4];
  const int tid = threadIdx.x;
  const int nt = blockIdx.x & 3;
  const int mt = blockIdx.x >> 2;
  const int m0 = mt * 128, n0 = nt * 128;
  const int tx = tid & 15, ty = tid >> 4;   // 16x16 thread grid, 8x8 micro-tile
  const int sr = tid >> 3, sc4 = tid & 7;   // staging: 32 rows x 8 float4-cols

  float bias[8];
#pragma unroll
  for (int j = 0; j < 8; ++j) {
    int n = n0 + tx * 8 + j;
    bias[j] = b_ih[n] + b_hh[n];
  }
  float acc[8][8];
#pragma unroll
  for (int i = 0; i < 8; ++i)
#pragma unroll
    for (int j = 0; j < 8; ++j) acc[i][j] = 0.f;

  for (int k0 = 0; k0 < F_SZ; k0 += 32) {
#pragma unroll
    for (int i = 0; i < 4; ++i) {
      int r = sr + 32 * i;
      float4 v = *(const float4*)(q + (size_t)(m0 + r) * F_SZ + k0 + sc4 * 4);
      lds_a[sc4 * 2 + 0][r] = pack2h(v.x, v.y);
      lds_a[sc4 * 2 + 1][r] = pack2h(v.z, v.w);
      float4 w = *(const float4*)(w_ih + (size_t)(n0 + r) * F_SZ + k0 + sc4 * 4);
      lds_b[sc4 * 2 + 0][r] = pack2h(w.x, w.y);
      lds_b[sc4 * 2 + 1][r] = pack2h(w.z, w.w);
    }
    __syncthreads();
#pragma unroll
    for (int kp = 0; kp < 16; ++kp) {
      uint32_t a8[8], b8[8];
#pragma unroll
      for (int i = 0; i < 8; ++i) a8[i] = lds_a[kp][ty * 8 + i];
#pragma unroll
      for (int j = 0; j < 8; ++j) b8[j] = lds_b[kp][tx * 8 + j];
#pragma unroll
      for (int i = 0; i < 8; ++i)
#pragma unroll
        for (int j = 0; j < 8; ++j)
          acc[i][j] = fdot2f(a8[i], b8[j], acc[i][j]);
    }
    __syncthreads();
  }
#pragma unroll
  for (int i = 0; i < 8; ++i) {
    size_t row = (size_t)(m0 + ty * 8 + i);
    float4 o0, o1;
    o0.x = acc[i][0] + bias[0]; o0.y = acc[i][1] + bias[1];
    o0.z = acc[i][2] + bias[2]; o0.w = acc[i][3] + bias[3];
    o1.x = acc[i][4] + bias[4]; o1.y = acc[i][5] + bias[5];
    o1.z = acc[i][6] + bias[6]; o1.w = acc[i][7] + bias[7];
    *(float4*)(xp + row * H_SZ + n0 + tx * 8) = o0;
    *(float4*)(xp + row * H_SZ + n0 + tx * 8 + 4) = o1;
  }
}

// ---------------------------------------------------------------------------
// Kernel 2: per-batch recurrence. One 512-thread WG per batch row (64 WGs).
// W_hh held fp16-resident per CU: rows 0..383 in VGPRs (192 regs/thread),
// rows 384..511 in LDS (128 KB, chunk-XOR swizzled). h double-buffered fp16
// in LDS. Thread (rg = tid>>3, cs = tid&7) covers rows {rg + 64*k, k=0..7}
// over columns [cs*64, cs*64+64); 7-shuffle reduce-scatter leaves lane cs
// with the full dot for row rg + 64*cs.
// ---------------------------------------------------------------------------
__global__ __launch_bounds__(512, 2) void rnn_kernel(
    const float* __restrict__ w_hh, float* __restrict__ out) {
  extern __shared__ char smem[];
  uint32_t* lds_w = (uint32_t*)smem;                    // [128][256] f16 pairs
  unsigned short* lds_h = (unsigned short*)(smem + 131072);  // [2][512]

  const int b = blockIdx.x;
  const int tid = threadIdx.x;
  const int cs = tid & 7;
  const int rg = tid >> 3;

  // --- load VGPR-resident W rows: row = rg + 64*vr, cols [cs*64, +64) ---
  uint32_t wv[6][32];
#pragma unroll
  for (int vr = 0; vr < 6; ++vr) {
    const float* src = w_hh + (size_t)(rg + 64 * vr) * H_SZ + cs * 64;
#pragma unroll
    for (int j4 = 0; j4 < 16; ++j4) {
      float4 v = *(const float4*)(src + j4 * 4);
      wv[vr][j4 * 2 + 0] = pack2h(v.x, v.y);
      wv[vr][j4 * 2 + 1] = pack2h(v.z, v.w);
    }
  }
  // --- load LDS-resident W rows 384..511 (swizzled) ---
  {
    const int lrow = tid >> 2;      // 0..127
    const int quarter = tid & 3;    // 0..3
    const float* src = w_hh + (size_t)(384 + lrow) * H_SZ + quarter * 128;
    uint32_t* dst = lds_w + lrow * 256;
#pragma unroll
    for (int j4 = 0; j4 < 32; ++j4) {
      float4 v = *(const float4*)(src + j4 * 4);
      int c0 = quarter * 64 + j4 * 2;
      dst[swz(c0, lrow)]     = pack2h(v.x, v.y);
      dst[swz(c0 + 1, lrow)] = pack2h(v.z, v.w);
    }
  }
  // h0 = 0
  lds_h[tid] = 0;
  lds_h[512 + tid] = 0;
  __syncthreads();

  const int row_w = rg + 64 * cs;  // the row this thread writes (bijective)
  float* outb = out + (size_t)b * T_SZ * H_SZ;
  float hlast = 0.f;
  float xpv = outb[row_w];  // xp for t=0

#pragma unroll 1
  for (int t = 0; t < T_SZ; ++t) {
    // prefetch next step's xp early (hides HBM latency under compute)
    float xp_next = 0.f;
    if (t + 1 < T_SZ) xp_next = outb[(size_t)(t + 1) * H_SZ + row_w];

    const uint32_t* hbuf = (const uint32_t*)(lds_h + (t & 1) * 512);
    float acc[8];
#pragma unroll
    for (int r = 0; r < 8; ++r) acc[r] = 0.f;

#pragma unroll
    for (int half = 0; half < 2; ++half) {
      uint32_t hv[16];
#pragma unroll
      for (int j = 0; j < 16; ++j) hv[j] = hbuf[cs * 32 + half * 16 + j];
      // VGPR rows
#pragma unroll
      for (int vr = 0; vr < 6; ++vr)
#pragma unroll
        for (int j = 0; j < 16; ++j)
          acc[vr] = fdot2f(wv[vr][half * 16 + j], hv[j], acc[vr]);
      // LDS rows
#pragma unroll
      for (int lr = 0; lr < 2; ++lr) {
        const uint32_t* wrow = lds_w + (rg + 64 * lr) * 256;
#pragma unroll
        for (int kc = 0; kc < 4; ++kc) {
          int chunk = (cs * 8 + half * 4 + kc) ^ (rg & 7);
          uint4 wq = *(const uint4*)(wrow + chunk * 4);
          acc[6 + lr] = fdot2f(wq.x, hv[kc * 4 + 0], acc[6 + lr]);
          acc[6 + lr] = fdot2f(wq.y, hv[kc * 4 + 1], acc[6 + lr]);
          acc[6 + lr] = fdot2f(wq.z, hv[kc * 4 + 2], acc[6 + lr]);
          acc[6 + lr] = fdot2f(wq.w, hv[kc * 4 + 3], acc[6 + lr]);
        }
      }
    }

    // reduce-scatter over the 8-lane column group: lane cs ends with row cs's
    // total. Static indexing only (no runtime array index -> no scratch).
    float r4[4];
#pragma unroll
    for (int p = 0; p < 4; ++p) {
      float a = acc[2 * p], c2 = acc[2 * p + 1];
      float sel = (cs & 1) ? c2 : a;
      float oth = (cs & 1) ? a : c2;
      r4[p] = sel + __shfl_xor(oth, 1, 64);
    }
    float r2[2];
#pragma unroll
    for (int p = 0; p < 2; ++p) {
      float a = r4[2 * p], c2 = r4[2 * p + 1];
      float sel = (cs & 2) ? c2 : a;
      float oth = (cs & 2) ? a : c2;
      r2[p] = sel + __shfl_xor(oth, 2, 64);
    }
    float sum;
    {
      float a = r2[0], c2 = r2[1];
      float sel = (cs & 4) ? c2 : a;
      float oth = (cs & 4) ? a : c2;
      sum = sel + __shfl_xor(oth, 4, 64);
    }

    float hnew = tanhf(xpv + sum);
    outb[(size_t)t * H_SZ + row_w] = hnew;          // overwrite xp with h_t
    lds_h[((t + 1) & 1) * 512 + row_w] = f16bits(hnew);
    hlast = hnew;
    xpv = xp_next;
    __syncthreads();
  }
  // hidden = h_{T-1} at offset B*T*H
  out[(size_t)B_SZ * T_SZ * H_SZ + (size_t)b * H_SZ + row_w] = hlast;
}

extern "C" void kernel_launch(void* const* d_in, const int* in_sizes, int n_in,
                              void* d_out, int out_size, void* d_ws,
                              size_t ws_size, hipStream_t stream) {
  (void)in_sizes; (void)n_in; (void)out_size; (void)d_ws; (void)ws_size;
  const float* q    = (const float*)d_in[0];
  const float* w_ih = (const float*)d_in[1];
  const float* w_hh = (const float*)d_in[2];
  const float* b_ih = (const float*)d_in[3];
  const float* b_hh = (const float*)d_in[4];
  float* out = (float*)d_out;

  // Phase 1: xp -> out[0 : B*T*H]  (in-place staging, replay-safe)
  proj_kernel<<<dim3((B_SZ * T_SZ / 128) * (H_SZ / 128)), dim3(256), 0,
                stream>>>(q, w_ih, b_ih, b_hh, out);

  // Phase 2: recurrence, one WG per batch row. 133120 B dynamic LDS (>64KB
  // needs the opt-in attribute; idempotent, host-side, capture-safe).
  hipFuncSetAttribute(reinterpret_cast<const void*>(rnn_kernel),
                      hipFuncAttributeMaxDynamicSharedMemorySize, 133120);
  rnn_kernel<<<dim3(B_SZ), dim3(512), 133120, stream>>>(w_hh, out);
}

// Round 2
// 3148.881 us; speedup vs baseline: 2.0802x; 2.0802x over previous
//
#include <hip/hip_runtime.h>
#include <cstdint>

#define B_SZ 64
#define T_SZ 2048
#define F_SZ 256
#define H_SZ 512

#if defined(__has_builtin)
#if __has_builtin(__builtin_amdgcn_fdot2)
#define HAVE_FDOT2 1
#endif
#endif
#ifndef HAVE_FDOT2
#define HAVE_FDOT2 0
#endif

typedef _Float16 half2v __attribute__((ext_vector_type(2)));

union H2U { uint32_t u; half2v h; _Float16 e[2]; };

__device__ __forceinline__ float fdot2f(uint32_t a, uint32_t b, float c) {
  H2U ua, ub; ua.u = a; ub.u = b;
#if HAVE_FDOT2
  return __builtin_amdgcn_fdot2(ua.h, ub.h, c, false);
#else
  return c + (float)ua.e[0] * (float)ub.e[0] + (float)ua.e[1] * (float)ub.e[1];
#endif
}

__device__ __forceinline__ uint32_t pack2h(float x, float y) {
  H2U v; v.e[0] = (_Float16)x; v.e[1] = (_Float16)y; return v.u;
}

__device__ __forceinline__ unsigned short f16bits(float x) {
  union { _Float16 h; unsigned short s; } v; v.h = (_Float16)x; return v.s;
}

// cross-lane helpers: xor1/xor2 on the VALU pipe (DPP quad_perm), xor4 via
// one ds_swizzle (BitMode xor=4).
template <int CTRL>
__device__ __forceinline__ float dpp_qperm(float x) {
  return __int_as_float(
      __builtin_amdgcn_mov_dpp(__float_as_int(x), CTRL, 0xF, 0xF, true));
}
__device__ __forceinline__ float swz_xor4(float x) {
  return __int_as_float(
      __builtin_amdgcn_ds_swizzle(__float_as_int(x), 0x101F));
}

// 16B-chunk XOR swizzle within a 256-dword W row (dword index domain).
__device__ __forceinline__ int swz(int c, int r) {
  return (((c >> 2) ^ (r & 7)) << 2) | (c & 3);
}

// ---------------------------------------------------------------------------
// Kernel 1: xp[m, n] = sum_k q[m,k] * W_ih[n,k] + b_ih[n] + b_hh[n]
// (unchanged from round 1 — passed, ~320 us, not the bottleneck)
// ---------------------------------------------------------------------------
__global__ __launch_bounds__(256) void proj_kernel(
    const float* __restrict__ q, const float* __restrict__ w_ih,
    const float* __restrict__ b_ih, const float* __restrict__ b_hh,
    float* __restrict__ xp) {
  __shared__ uint32_t lds_a[16][128 + 4];
  __shared__ uint32_t lds_b[16][128 + 4];
  const int tid = threadIdx.x;
  const int nt = blockIdx.x & 3;
  const int mt = blockIdx.x >> 2;
  const int m0 = mt * 128, n0 = nt * 128;
  const int tx = tid & 15, ty = tid >> 4;
  const int sr = tid >> 3, sc4 = tid & 7;

  float bias[8];
#pragma unroll
  for (int j = 0; j < 8; ++j) {
    int n = n0 + tx * 8 + j;
    bias[j] = b_ih[n] + b_hh[n];
  }
  float acc[8][8];
#pragma unroll
  for (int i = 0; i < 8; ++i)
#pragma unroll
    for (int j = 0; j < 8; ++j) acc[i][j] = 0.f;

  for (int k0 = 0; k0 < F_SZ; k0 += 32) {
#pragma unroll
    for (int i = 0; i < 4; ++i) {
      int r = sr + 32 * i;
      float4 v = *(const float4*)(q + (size_t)(m0 + r) * F_SZ + k0 + sc4 * 4);
      lds_a[sc4 * 2 + 0][r] = pack2h(v.x, v.y);
      lds_a[sc4 * 2 + 1][r] = pack2h(v.z, v.w);
      float4 w = *(const float4*)(w_ih + (size_t)(n0 + r) * F_SZ + k0 + sc4 * 4);
      lds_b[sc4 * 2 + 0][r] = pack2h(w.x, w.y);
      lds_b[sc4 * 2 + 1][r] = pack2h(w.z, w.w);
    }
    __syncthreads();
#pragma unroll
    for (int kp = 0; kp < 16; ++kp) {
      uint32_t a8[8], b8[8];
#pragma unroll
      for (int i = 0; i < 8; ++i) a8[i] = lds_a[kp][ty * 8 + i];
#pragma unroll
      for (int j = 0; j < 8; ++j) b8[j] = lds_b[kp][tx * 8 + j];
#pragma unroll
      for (int i = 0; i < 8; ++i)
#pragma unroll
        for (int j = 0; j < 8; ++j)
          acc[i][j] = fdot2f(a8[i], b8[j], acc[i][j]);
    }
    __syncthreads();
  }
#pragma unroll
  for (int i = 0; i < 8; ++i) {
    size_t row = (size_t)(m0 + ty * 8 + i);
    float4 o0, o1;
    o0.x = acc[i][0] + bias[0]; o0.y = acc[i][1] + bias[1];
    o0.z = acc[i][2] + bias[2]; o0.w = acc[i][3] + bias[3];
    o1.x = acc[i][4] + bias[4]; o1.y = acc[i][5] + bias[5];
    o1.z = acc[i][6] + bias[6]; o1.w = acc[i][7] + bias[7];
    *(float4*)(xp + row * H_SZ + n0 + tx * 8) = o0;
    *(float4*)(xp + row * H_SZ + n0 + tx * 8 + 4) = o1;
  }
}

// ---------------------------------------------------------------------------
// Kernel 2: per-batch recurrence. 512 threads, one WG per batch row.
// W_hh fp16: rows 0..383 in VGPRs (192 regs/thread, 2 waves/SIMD pinned),
// rows 384..511 in LDS (128 KB, chunk-XOR swizzled).
// h fp16 pairs in LDS at stride-36 dwords per column-slice -> conflict-free
// b128 broadcast reads. Reduce-scatter: DPP xor1/xor2 + ds_swizzle xor4.
// ---------------------------------------------------------------------------
__global__ __attribute__((amdgpu_flat_work_group_size(512, 512),
                          amdgpu_waves_per_eu(2, 2)))
void rnn_kernel(const float* __restrict__ w_hh, float* __restrict__ out) {
  extern __shared__ char smem[];
  uint32_t* lds_w = (uint32_t*)smem;                 // [128][256] f16-pair dwords
  uint32_t* lds_h = (uint32_t*)(smem + 131072);      // 2 x (8 slices x 36 dwords)

  const int b = blockIdx.x;
  const int tid = threadIdx.x;
  const int cs = tid & 7;
  const int rg = tid >> 3;
  const int r3 = rg & 7;

  // --- VGPR-resident W rows: row = rg + 64*vr, cols [cs*64, +64) ---
  uint32_t wv[6][32];
#pragma unroll
  for (int vr = 0; vr < 6; ++vr) {
    const float* src = w_hh + (size_t)(rg + 64 * vr) * H_SZ + cs * 64;
#pragma unroll
    for (int j4 = 0; j4 < 16; ++j4) {
      float4 v = *(const float4*)(src + j4 * 4);
      wv[vr][j4 * 2 + 0] = pack2h(v.x, v.y);
      wv[vr][j4 * 2 + 1] = pack2h(v.z, v.w);
    }
  }
  // --- LDS-resident W rows 384..511 (16B-chunk swizzled) ---
  {
    const int lrow = tid >> 2;      // 0..127
    const int quarter = tid & 3;    // 0..3
    const float* src = w_hh + (size_t)(384 + lrow) * H_SZ + quarter * 128;
    uint32_t* dst = lds_w + lrow * 256;
#pragma unroll
    for (int j4 = 0; j4 < 32; ++j4) {
      float4 v = *(const float4*)(src + j4 * 4);
      int c0 = quarter * 64 + j4 * 2;
      dst[swz(c0, lrow)]     = pack2h(v.x, v.y);
      dst[swz(c0 + 1, lrow)] = pack2h(v.z, v.w);
    }
  }
  // h0 = 0 (both buffers, 576 dwords)
  lds_h[tid] = 0;
  if (tid < 64) lds_h[512 + tid] = 0;
  __syncthreads();

  const int row_w = rg + 64 * cs;  // bijective thread -> output row
  float* outb = out + (size_t)b * T_SZ * H_SZ;
  float hlast = 0.f;
  float xpv = outb[row_w];  // xp for t=0

#pragma unroll 1
  for (int t = 0; t < T_SZ; ++t) {
    float xp_next = (t + 1 < T_SZ) ? outb[(size_t)(t + 1) * H_SZ + row_w] : 0.f;

    const uint32_t* hbuf = lds_h + (t & 1) * 288 + cs * 36;
    const uint32_t* wrow0 = lds_w + rg * 256;          // global row 384+rg
    const uint32_t* wrow1 = lds_w + (rg + 64) * 256;   // global row 448+rg

    float acc[8];
#pragma unroll
    for (int r = 0; r < 8; ++r) acc[r] = 0.f;

#pragma unroll
    for (int qq = 0; qq < 4; ++qq) {
      uint4 ha = *(const uint4*)(hbuf + qq * 8);      // pairs 8qq..8qq+3
      uint4 hb = *(const uint4*)(hbuf + qq * 8 + 4);  // pairs 8qq+4..8qq+7
#pragma unroll
      for (int vr = 0; vr < 6; ++vr) {
        acc[vr] = fdot2f(wv[vr][qq * 8 + 0], ha.x, acc[vr]);
        acc[vr] = fdot2f(wv[vr][qq * 8 + 1], ha.y, acc[vr]);
        acc[vr] = fdot2f(wv[vr][qq * 8 + 2], ha.z, acc[vr]);
        acc[vr] = fdot2f(wv[vr][qq * 8 + 3], ha.w, acc[vr]);
        acc[vr] = fdot2f(wv[vr][qq * 8 + 4], hb.x, acc[vr]);
        acc[vr] = fdot2f(wv[vr][qq * 8 + 5], hb.y, acc[vr]);
        acc[vr] = fdot2f(wv[vr][qq * 8 + 6], hb.z, acc[vr]);
        acc[vr] = fdot2f(wv[vr][qq * 8 + 7], hb.w, acc[vr]);
      }
      {
        uint4 wq = *(const uint4*)(wrow0 + (cs * 8 + ((2 * qq + 0) ^ r3)) * 4);
        acc[6] = fdot2f(wq.x, ha.x, acc[6]);
        acc[6] = fdot2f(wq.y, ha.y, acc[6]);
        acc[6] = fdot2f(wq.z, ha.z, acc[6]);
        acc[6] = fdot2f(wq.w, ha.w, acc[6]);
      }
      {
        uint4 wq = *(const uint4*)(wrow0 + (cs * 8 + ((2 * qq + 1) ^ r3)) * 4);
        acc[6] = fdot2f(wq.x, hb.x, acc[6]);
        acc[6] = fdot2f(wq.y, hb.y, acc[6]);
        acc[6] = fdot2f(wq.z, hb.z, acc[6]);
        acc[6] = fdot2f(wq.w, hb.w, acc[6]);
      }
      {
        uint4 wq = *(const uint4*)(wrow1 + (cs * 8 + ((2 * qq + 0) ^ r3)) * 4);
        acc[7] = fdot2f(wq.x, ha.x, acc[7]);
        acc[7] = fdot2f(wq.y, ha.y, acc[7]);
        acc[7] = fdot2f(wq.z, ha.z, acc[7]);
        acc[7] = fdot2f(wq.w, ha.w, acc[7]);
      }
      {
        uint4 wq = *(const uint4*)(wrow1 + (cs * 8 + ((2 * qq + 1) ^ r3)) * 4);
        acc[7] = fdot2f(wq.x, hb.x, acc[7]);
        acc[7] = fdot2f(wq.y, hb.y, acc[7]);
        acc[7] = fdot2f(wq.z, hb.z, acc[7]);
        acc[7] = fdot2f(wq.w, hb.w, acc[7]);
      }
    }

    // reduce-scatter across the 8-lane column group; lane cs keeps row
    // rg + 64*cs. xor1/xor2 on DPP (VALU), xor4 on ds_swizzle.
    float r4[4];
#pragma unroll
    for (int p = 0; p < 4; ++p) {
      float a = acc[2 * p], c2 = acc[2 * p + 1];
      float sel = (cs & 1) ? c2 : a;
      float oth = (cs & 1) ? a : c2;
      r4[p] = sel + dpp_qperm<0xB1>(oth);  // quad_perm [1,0,3,2] = xor1
    }
    float r2[2];
#pragma unroll
    for (int p = 0; p < 2; ++p) {
      float a = r4[2 * p], c2 = r4[2 * p + 1];
      float sel = (cs & 2) ? c2 : a;
      float oth = (cs & 2) ? a : c2;
      r2[p] = sel + dpp_qperm<0x4E>(oth);  // quad_perm [2,3,0,1] = xor2
    }
    float sum;
    {
      float a = r2[0], c2 = r2[1];
      float sel = (cs & 4) ? c2 : a;
      float oth = (cs & 4) ? a : c2;
      sum = sel + swz_xor4(oth);
    }

    // fast tanh: (e^2x - 1) / (e^2x + 1), clamped (branchless, no libm)
    float x = xpv + sum;
    float xc = fminf(9.0f, fmaxf(-9.0f, x));
    float e = __expf(2.0f * xc);
    float hnew = (e - 1.0f) / (e + 1.0f);

    outb[(size_t)t * H_SZ + row_w] = hnew;  // overwrite xp with h_t
    {
      uint32_t* hwbuf = lds_h + (((t + 1) & 1) * 288);
      ((unsigned short*)hwbuf)[(cs * 36 + (rg >> 1)) * 2 + (rg & 1)] =
          f16bits(hnew);
    }
    hlast = hnew;
    xpv = xp_next;
    __syncthreads();
  }
  // hidden = h_{T-1} at offset B*T*H
  out[(size_t)B_SZ * T_SZ * H_SZ + (size_t)b * H_SZ + row_w] = hlast;
}

extern "C" void kernel_launch(void* const* d_in, const int* in_sizes, int n_in,
                              void* d_out, int out_size, void* d_ws,
                              size_t ws_size, hipStream_t stream) {
  (void)in_sizes; (void)n_in; (void)out_size; (void)d_ws; (void)ws_size;
  const float* q    = (const float*)d_in[0];
  const float* w_ih = (const float*)d_in[1];
  const float* w_hh = (const float*)d_in[2];
  const float* b_ih = (const float*)d_in[3];
  const float* b_hh = (const float*)d_in[4];
  float* out = (float*)d_out;

  proj_kernel<<<dim3((B_SZ * T_SZ / 128) * (H_SZ / 128)), dim3(256), 0,
                stream>>>(q, w_ih, b_ih, b_hh, out);

  // 131072 (W) + 2*288*4 (h dbuf) = 133376 B dynamic LDS
  hipFuncSetAttribute(reinterpret_cast<const void*>(rnn_kernel),
                      hipFuncAttributeMaxDynamicSharedMemorySize, 133376);
  rnn_kernel<<<dim3(B_SZ), dim3(512), 133376, stream>>>(w_hh, out);
}